// Round 1
// 1411.882 us; speedup vs baseline: 1.0190x; 1.0190x over previous
//
#include <hip/hip_runtime.h>
#include <stdint.h>

// 1 = partitionable threefry (JAX >= 0.4.36 default): bits = y0 ^ y1 of TF((0,42),(0,i))
// 0 = original/legacy scheme: concat of halves
#ifndef GUMBEL_SCHEME
#define GUMBEL_SCHEME 1
#endif

constexpr int B_ = 64;
constexpr int D_ = 4096;
constexpr int V_ = 50257;

// ---------------- Threefry-2x32-20, key = (0, 42) ----------------
__device__ __forceinline__ void tf_round(uint32_t& x0, uint32_t& x1, int r) {
  x0 += x1;
  x1 = (x1 << r) | (x1 >> (32 - r));
  x1 ^= x0;
}

__device__ __forceinline__ void threefry2x32(uint32_t xx0, uint32_t xx1,
                                             uint32_t& y0, uint32_t& y1) {
  const uint32_t k0 = 0u, k1 = 42u;
  const uint32_t k2 = 0x1BD11BDAu ^ k0 ^ k1;
  uint32_t x0 = xx0 + k0, x1 = xx1 + k1;
  tf_round(x0, x1, 13); tf_round(x0, x1, 15); tf_round(x0, x1, 26); tf_round(x0, x1, 6);
  x0 += k1; x1 += k2 + 1u;
  tf_round(x0, x1, 17); tf_round(x0, x1, 29); tf_round(x0, x1, 16); tf_round(x0, x1, 24);
  x0 += k2; x1 += k0 + 2u;
  tf_round(x0, x1, 13); tf_round(x0, x1, 15); tf_round(x0, x1, 26); tf_round(x0, x1, 6);
  x0 += k0; x1 += k1 + 3u;
  tf_round(x0, x1, 17); tf_round(x0, x1, 29); tf_round(x0, x1, 16); tf_round(x0, x1, 24);
  x0 += k1; x1 += k2 + 4u;
  tf_round(x0, x1, 13); tf_round(x0, x1, 15); tf_round(x0, x1, 26); tf_round(x0, x1, 6);
  x0 += k2; x1 += k0 + 5u;
  y0 = x0; y1 = x1;
}

__device__ __forceinline__ uint32_t rand_bits(uint32_t flat_idx) {
  uint32_t y0, y1;
#if GUMBEL_SCHEME
  threefry2x32(0u, flat_idx, y0, y1);
  return y0 ^ y1;
#else
  const uint32_t HALF = (uint32_t)(B_ * (long)V_ / 2);  // 1608224
  uint32_t j = (flat_idx < HALF) ? flat_idx : flat_idx - HALF;
  threefry2x32(j, j + HALF, y0, y1);
  return (flat_idx < HALF) ? y0 : y1;
#endif
}

__device__ __forceinline__ float gumbel_from_bits(uint32_t r) {
  // u = max(tiny, bitcast((r>>9)|0x3f800000) - 1)  (exactly JAX's uniform in fp32)
  float f = __uint_as_float((r >> 9) | 0x3F800000u) - 1.0f;
  float u = fmaxf(1.17549435e-38f, f);
  return -logf(-logf(u));
}

// ---------------- monotone fp32<->uint32 ----------------
__device__ __forceinline__ uint32_t f2mono(float f) {
  uint32_t u = __float_as_uint(f);
  return u ^ (0x80000000u | (uint32_t)((int32_t)u >> 31));
}
__device__ __forceinline__ float mono2f(uint32_t m) {
  uint32_t u = (m & 0x80000000u) ? (m ^ 0x80000000u) : ~m;
  return __uint_as_float(u);
}

// ======================= GEMM: logits += H @ W^T (split-K, raw sums) =========
// 64(batch) x 128(vocab) tile, BK=64, 256 threads, 4x8 per thread.
// Split-K x2 over blockIdx.y -> 786 blocks = ~3 blocks/CU (12 waves/CU).
// Temperature division is applied in topp_sample on load.
constexpr int SPLITK = 2;
constexpr int KSEG = D_ / SPLITK;  // 2048

__global__ __launch_bounds__(256, 3) void gemm_logits(
    const float* __restrict__ H, const float* __restrict__ W,
    float* __restrict__ logits) {
  constexpr int TN = 128, BK = 64;
  __shared__ float Ash[64][BK + 4];   // [batch][k], stride 68 (16B-aligned rows)
  __shared__ float Bsh[BK][TN + 4];   // [k][vocab], stride 132, XOR-quad swizzled
  // Swizzle: column-quad q of row k is stored at q ^ ((k>>2)&7).
  // Transpose stores then hit all 32 banks 2-way (free) instead of 8-way,
  // and reads stay 16B-aligned ds_read_b128 (132*4 % 16 == 0).

  const int tid = threadIdx.x;
  const int tx = tid & 15;   // vocab group
  const int ty = tid >> 4;   // batch group
  const int n0 = blockIdx.x * TN;
  const int kbeg = blockIdx.y * KSEG;

  float acc[4][8];
#pragma unroll
  for (int i = 0; i < 4; i++)
#pragma unroll
    for (int j = 0; j < 8; j++) acc[i][j] = 0.f;

  for (int k0 = kbeg; k0 < kbeg + KSEG; k0 += BK) {
    // stage A: 64 x 64, row-major, vector stores
#pragma unroll
    for (int i = 0; i < 4; i++) {
      const int li = tid + i * 256;
      const int row = li >> 4, c4 = li & 15;
      const float4 v = *(const float4*)(H + (size_t)row * D_ + k0 + (c4 << 2));
      *(float4*)&Ash[row][c4 << 2] = v;
    }
    // stage B: 128 x 64, transposed into [k][vocab], swizzled columns
#pragma unroll
    for (int i = 0; i < 8; i++) {
      const int li = tid + i * 256;
      const int row = li >> 4, c4 = li & 15;   // row = vocab col, c4 = k-quad
      int gr = n0 + row; gr = (gr < V_) ? gr : (V_ - 1);
      const float4 v = *(const float4*)(W + (size_t)gr * D_ + k0 + (c4 << 2));
      const int sw = ((((row >> 2) ^ (c4 & 7)) << 2) | (row & 3));
      Bsh[(c4 << 2) + 0][sw] = v.x;
      Bsh[(c4 << 2) + 1][sw] = v.y;
      Bsh[(c4 << 2) + 2][sw] = v.z;
      Bsh[(c4 << 2) + 3][sw] = v.w;
    }
    __syncthreads();
#pragma unroll
    for (int kk = 0; kk < BK; kk += 4) {
      const int cxor = (kk >> 2) & 7;          // same for kk..kk+3
      const int qb = (tx ^ cxor) << 2;
      float4 a[4], b0[4], b1[4];
#pragma unroll
      for (int i2 = 0; i2 < 4; i2++) a[i2] = *(const float4*)&Ash[(ty << 2) + i2][kk];
#pragma unroll
      for (int t = 0; t < 4; t++) {
        b0[t] = *(const float4*)&Bsh[kk + t][qb];
        b1[t] = *(const float4*)&Bsh[kk + t][64 + qb];
      }
#pragma unroll
      for (int i2 = 0; i2 < 4; i2++) {
#pragma unroll
        for (int t = 0; t < 4; t++) {
          const float av = ((const float*)&a[i2])[t];
          const float* bp0 = (const float*)&b0[t];
          const float* bp1 = (const float*)&b1[t];
#pragma unroll
          for (int j = 0; j < 4; j++) {
            acc[i2][j]     = fmaf(av, bp0[j], acc[i2][j]);
            acc[i2][j + 4] = fmaf(av, bp1[j], acc[i2][j + 4]);
          }
        }
      }
    }
    __syncthreads();
  }

  // epilogue: accumulate raw partial sums (fp32 add is commutative ->
  // result independent of which K-half lands first; buffer pre-zeroed)
#pragma unroll
  for (int i2 = 0; i2 < 4; i2++) {
    const int mrow = (ty << 2) + i2;
#pragma unroll
    for (int j = 0; j < 8; j++) {
      const int n = n0 + ((j < 4) ? ((tx << 2) + j) : (64 + (tx << 2) + (j - 4)));
      if (n < V_) atomicAdd(&logits[(size_t)mrow * V_ + n], acc[i2][j]);
    }
  }
}

// ======================= workspace zero (graph-safe, no hipMemset) ===========
__global__ __launch_bounds__(256) void zero_ws(float4* __restrict__ p, int n4) {
  int i = blockIdx.x * blockDim.x + threadIdx.x;
  const int stride = gridDim.x * blockDim.x;
  for (; i < n4; i += stride) p[i] = make_float4(0.f, 0.f, 0.f, 0.f);
}

// ======================= fused top-p mask + gumbel argmax =======================
constexpr int TPB = 1024;
constexpr int NPER = (V_ + TPB - 1) / TPB;  // 50
static_assert(NPER * TPB >= V_, "coverage");
constexpr int NB1 = 4096;                   // level-1/2 histogram buckets

__device__ float blk_reduce_sum(float v, volatile float* red, float* bc) {
  const int tid = threadIdx.x;
#pragma unroll
  for (int off = 32; off > 0; off >>= 1) v += __shfl_down(v, off);
  if ((tid & 63) == 0) red[tid >> 6] = v;
  __syncthreads();
  if (tid == 0) {
    float s = 0.f;
#pragma unroll
    for (int w = 0; w < 16; w++) s += red[w];
    *bc = s;
  }
  __syncthreads();
  const float r = *bc;
  __syncthreads();
  return r;
}

__device__ float blk_reduce_max(float v, volatile float* red, float* bc) {
  const int tid = threadIdx.x;
#pragma unroll
  for (int off = 32; off > 0; off >>= 1) v = fmaxf(v, __shfl_down(v, off));
  if ((tid & 63) == 0) red[tid >> 6] = v;
  __syncthreads();
  if (tid == 0) {
    float s = -INFINITY;
#pragma unroll
    for (int w = 0; w < 16; w++) s = fmaxf(s, red[w]);
    *bc = s;
  }
  __syncthreads();
  const float r = *bc;
  __syncthreads();
  return r;
}

// Radix-select level: given integer-mass histogram hist[0..NB), pick the
// LOWEST non-empty bucket b with (mass strictly above b) <= P.
// Exact u64 arithmetic -> deterministic, order-independent.
// If frac >= 0, P is computed as frac * Total (level 1: P = top_p * Z).
__device__ void level_select(unsigned long long* hist, int NB,
                             unsigned long long P_in, double frac, int tid,
                             unsigned long long* wsum, int* selb_p,
                             unsigned long long* selA_p,
                             int& b_out, unsigned long long& A_out,
                             unsigned long long& Tot_out,
                             unsigned long long& P_out) {
  const int lane = tid & 63, wid = tid >> 6;
  const int nchunk = NB >> 2;       // 4 buckets per participating thread
  const int nwav = nchunk >> 6;
  unsigned long long c = 0ull;
  if (tid < nchunk)
    c = hist[4 * tid] + hist[4 * tid + 1] + hist[4 * tid + 2] + hist[4 * tid + 3];
  unsigned long long x = c;         // wave-inclusive scan of chunk sums
#pragma unroll
  for (int off = 1; off < 64; off <<= 1) {
    unsigned long long y = __shfl_up(x, (unsigned int)off);
    if (lane >= off) x += y;
  }
  if (tid < nchunk && lane == 63) wsum[wid] = x;
  if (tid == 0) *selb_p = 0x7FFFFFFF;
  __syncthreads();
  unsigned long long woff = 0ull, Tot = 0ull;
  for (int w = 0; w < nwav; w++) {
    const unsigned long long ws = wsum[w];
    if (w < wid) woff += ws;
    Tot += ws;
  }
  const unsigned long long P =
      (frac >= 0.0) ? (unsigned long long)(frac * (double)Tot) : P_in;
  if (tid < nchunk) {
    unsigned long long cs = woff + (x - c);   // exclusive prefix (exact ints)
    for (int j = 0; j < 4; j++) {
      const unsigned long long hv = hist[4 * tid + j];
      cs += hv;                               // inclusive through bucket
      if (hv > 0ull && (Tot - cs) <= P) atomicMin(selb_p, 4 * tid + j);
    }
  }
  __syncthreads();
  const int sb = *selb_p;
  if (tid == (sb >> 2)) {
    unsigned long long cs = woff + (x - c);
    for (int j = 0; j <= (sb & 3); j++) cs += hist[4 * tid + j];
    *selA_p = Tot - cs;                       // mass strictly above bucket sb
  }
  __syncthreads();
  b_out = sb;
  A_out = *selA_p;
  Tot_out = Tot;
  P_out = P;
  __syncthreads();                            // safe to reuse hist/wsum/sel*
}

__global__ __launch_bounds__(TPB) void topp_sample(
    const float* __restrict__ logits, const float* __restrict__ T,
    const float* __restrict__ top_p, int* __restrict__ out) {
  __shared__ float red[16];
  __shared__ float bcf;
  __shared__ unsigned long long hist[NB1];
  __shared__ unsigned long long wsum[16];
  __shared__ int selb;
  __shared__ unsigned long long selA;
  __shared__ float redv[16];
  __shared__ int redi[16];
  __shared__ int wct[16];
  __shared__ int runbase;

  const int b = blockIdx.x;
  const int tid = threadIdx.x;
  const int lane = tid & 63, wid = tid >> 6;
  const float tb = T[b];
  const float* __restrict__ L = logits + (size_t)b * V_;

  // logits/temperature (IEEE div, matching the reference's logits/temp)
  float l[NPER];
#pragma unroll
  for (int i = 0; i < NPER; i++) {
    const int v = tid + i * TPB;
    l[i] = (v < V_) ? (L[v] / tb) : -INFINITY;
  }

  // row max
  float m0 = -INFINITY;
#pragma unroll
  for (int i = 0; i < NPER; i++) m0 = fmaxf(m0, l[i]);
  const float M = blk_reduce_max(m0, red, &bcf);

  // ---- 3-level radix select of cstar on the monotone key (12+12+8 bits) ----
  // Masses are fixed-point u64: E = (u64)(exp(l-M) * 2^32)  (exact atomics).
  int b1, b2, b3;
  unsigned long long A1, A2, A3, Tot1, TotD, P1, P2, P3, PD;

  // level 1: key = mono >> 20
  for (int k = tid; k < NB1; k += TPB) hist[k] = 0ull;
  __syncthreads();
#pragma unroll
  for (int i = 0; i < NPER; i++) {
    const int v = tid + i * TPB;
    if (v < V_) {
      const uint32_t mm = f2mono(l[i]);
      const float e = expf(l[i] - M);
      atomicAdd(&hist[mm >> 20], (unsigned long long)(e * 4294967296.0f));
    }
  }
  __syncthreads();
  level_select(hist, NB1, 0ull, (double)top_p[b], tid, wsum, &selb, &selA,
               b1, A1, Tot1, P1);

  // level 2: key = (mono >> 8) & 0xFFF, restricted to bucket b1
  for (int k = tid; k < NB1; k += TPB) hist[k] = 0ull;
  __syncthreads();
#pragma unroll
  for (int i = 0; i < NPER; i++) {
    const int v = tid + i * TPB;
    if (v < V_) {
      const uint32_t mm = f2mono(l[i]);
      if ((int)(mm >> 20) == b1) {
        const float e = expf(l[i] - M);
        atomicAdd(&hist[(mm >> 8) & 0xFFFu], (unsigned long long)(e * 4294967296.0f));
      }
    }
  }
  __syncthreads();
  P2 = P1 - A1;
  level_select(hist, NB1, P2, -1.0, tid, wsum, &selb, &selA, b2, A2, TotD, PD);

  // level 3: key = mono & 0xFF, restricted to (b1,b2)
  for (int k = tid; k < 256; k += TPB) hist[k] = 0ull;
  __syncthreads();
  const uint32_t hi24 = ((uint32_t)b1 << 12) | (uint32_t)b2;
#pragma unroll
  for (int i = 0; i < NPER; i++) {
    const int v = tid + i * TPB;
    if (v < V_) {
      const uint32_t mm = f2mono(l[i]);
      if ((mm >> 8) == hi24) {
        const float e = expf(l[i] - M);
        atomicAdd(&hist[mm & 0xFFu], (unsigned long long)(e * 4294967296.0f));
      }
    }
  }
  __syncthreads();
  P3 = P2 - A2;
  level_select(hist, 256, P3, -1.0, tid, wsum, &selb, &selA, b3, A3, TotD, PD);

  const uint32_t cmono = ((uint32_t)b1 << 20) | ((uint32_t)b2 << 8) | (uint32_t)b3;
  const float cstar = mono2f(cmono);

  // ---- float-space finish: identical semantics to the verified kernel ----
  // Z, s_hi, n_tie with the same per-thread accumulation order as before.
  float zl = 0.f, sl = 0.f, ntl = 0.f;
#pragma unroll
  for (int i = 0; i < NPER; i++) {
    const float e = expf(l[i] - M);           // exp(-inf)=0 handles tail
    zl += e;
    sl += (l[i] > cstar) ? e : 0.f;
    ntl += (l[i] == cstar) ? 1.f : 0.f;
  }
  const float Z = blk_reduce_sum(zl, red, &bcf);
  const float s_hi = blk_reduce_sum(sl, red, &bcf);
  const int n_tie = (int)blk_reduce_sum(ntl, red, &bcf);
  const float P = top_p[b] * Z;               // compare cumsums in exp-numerator space

  // ties at cstar: keep first kk in index order (stable sort semantics)
  const float p_num = expf(cstar - M);
  int kk = 0;
  {
    float s = s_hi;
    for (int j = 0; j < n_tie; j++) {
      if (s <= P) { kk++; s += p_num; } else break;
    }
  }
  if (kk < n_tie) {
    // mask ties with index-rank >= kk (in registers; no global round-trip)
    if (tid == 0) runbase = 0;
    __syncthreads();
#pragma unroll
    for (int i = 0; i < NPER; i++) {
      const int v = tid + i * TPB;
      const bool tie = (v < V_) && (l[i] == cstar);
      const unsigned long long mk = __ballot(tie);
      if (lane == 0) wct[wid] = __popcll(mk);
      __syncthreads();
      int pre = runbase;
      for (int w = 0; w < wid; w++) pre += wct[w];
      if (lane) pre += __popcll(mk & ((~0ull) >> (64 - lane)));
      if (tie && pre >= kk) l[i] = -INFINITY;
      __syncthreads();
      if (tid == 0) {
        int t = 0;
        for (int w = 0; w < 16; w++) t += wct[w];
        runbase += t;
      }
      __syncthreads();
    }
  }

  // gumbel + argmax over kept set (lv >= cstar; masked ties are -inf)
  float best = -INFINITY;
  int bidx = 0x7FFFFFFF;
#pragma unroll
  for (int i = 0; i < NPER; i++) {
    const int v = tid + i * TPB;
    if (v < V_) {
      const float lv = l[i];
      const uint32_t gi = (uint32_t)(b * V_ + v);
      const float g = gumbel_from_bits(rand_bits(gi));
      const float val = (lv >= cstar) ? (g + lv) : -INFINITY;
      if (val > best) { best = val; bidx = v; }
    }
  }
#pragma unroll
  for (int off = 32; off > 0; off >>= 1) {
    const float ov = __shfl_down(best, off);
    const int oi = __shfl_down(bidx, off);
    if (ov > best || (ov == best && oi < bidx)) { best = ov; bidx = oi; }
  }
  if (lane == 0) { redv[wid] = best; redi[wid] = bidx; }
  __syncthreads();
  if (tid == 0) {
    float bv = redv[0]; int bi = redi[0];
    for (int w = 1; w < 16; w++)
      if (redv[w] > bv || (redv[w] == bv && redi[w] < bi)) { bv = redv[w]; bi = redi[w]; }
    out[b] = bi;
  }
}

// ======================= launch =======================
extern "C" void kernel_launch(void* const* d_in, const int* in_sizes, int n_in,
                              void* d_out, int out_size, void* d_ws, size_t ws_size,
                              hipStream_t stream) {
  const float* H = (const float*)d_in[0];     // [64, 4096]
  const float* W = (const float*)d_in[1];     // [50257, 4096]
  const float* T = (const float*)d_in[2];     // [64]
  const float* topp = (const float*)d_in[3];  // [64]
  float* logits = (float*)d_ws;               // 64*50257 floats = 12.87 MB
  int* out = (int*)d_out;

  const int n4 = (B_ * V_) / 4;               // 804112, exact
  zero_ws<<<dim3(2048), dim3(256), 0, stream>>>((float4*)logits, n4);

  const int nblk = (V_ + 127) / 128;          // 393 vocab tiles x 2 K-halves
  gemm_logits<<<dim3(nblk, SPLITK), dim3(256), 0, stream>>>(H, W, logits);
  topp_sample<<<dim3(B_), dim3(TPB), 0, stream>>>(logits, T, topp, out);
}